// Round 1
// baseline (145.601 us; speedup 1.0000x reference)
//
#include <hip/hip_runtime.h>
#include <stdint.h>

// KANLinear: y = silu(x) @ W_b^T + einsum('big,oig->bo', bases(x), W_s * scaler)
// Strategy: materialize Act = [silu(x) | bases] (B x 4608) bf16 and
// Wc = [W_b | W_s*scaler] (512 x 4608) bf16, then one bf16 MFMA GEMM (m97 structure).

#define IN_F   512
#define OUT_F  512
#define NB     8                     // GRID_SIZE + SPLINE_ORDER
#define KDIM   (IN_F + IN_F * NB)    // 4608
#define BATCH  16384

#define BM 128
#define BN 128
#define BK 64

typedef unsigned short u16;
typedef short s16x8 __attribute__((ext_vector_type(8)));
typedef float f32x4 __attribute__((ext_vector_type(4)));

__device__ __forceinline__ u16 f2bf(float f) {
    uint32_t u = __builtin_bit_cast(uint32_t, f);
    uint32_t r = (u + 0x7FFFu + ((u >> 16) & 1u)) >> 16;   // RNE
    return (u16)r;
}

// ---------------- weight prep: Wc[o][k] bf16, k<512 base, else spline*scaler ----
__global__ void prep_w_kernel(const float* __restrict__ bw,
                              const float* __restrict__ sw,
                              const float* __restrict__ sc,
                              u16* __restrict__ Wc) {
    int idx = blockIdx.x * 256 + threadIdx.x;      // (o,i), 512*512 threads
    int o = idx >> 9;
    int i = idx & 511;
    Wc[(size_t)o * KDIM + i] = f2bf(bw[idx]);
    float s = sc[idx];
    const float4* sp = reinterpret_cast<const float4*>(sw + (size_t)idx * 8);
    float4 a = sp[0];
    float4 b = sp[1];
    union { u16 us[8]; uint4 v; } pk;
    pk.us[0] = f2bf(a.x * s); pk.us[1] = f2bf(a.y * s);
    pk.us[2] = f2bf(a.z * s); pk.us[3] = f2bf(a.w * s);
    pk.us[4] = f2bf(b.x * s); pk.us[5] = f2bf(b.y * s);
    pk.us[6] = f2bf(b.z * s); pk.us[7] = f2bf(b.w * s);
    *reinterpret_cast<uint4*>(Wc + (size_t)o * KDIM + IN_F + (size_t)i * 8) = pk.v;
}

// ---------------- activation prep: Act[b][0..511]=silu, [512+8i+g]=bases -------
// Uniform knots t_j = -2.2 + 0.4*j (j=0..11); x in [t_2, t_9) after clipping.
__global__ void prep_x_kernel(const float* __restrict__ x,
                              u16* __restrict__ Act) {
    int idx = blockIdx.x * 256 + threadIdx.x;      // (b,i), BATCH*IN_F threads
    int b = idx >> 9;
    int i = idx & 511;
    float v = x[idx];
    if (v != v) v = 0.0f;                          // nan -> 0
    v = fminf(fmaxf(v, -6.0f), 6.0f);              // also folds +-inf
    v = fminf(fmaxf(v, -1.1f), 1.1f);              // grid clamp
    // renormalize: (x+1)/(2+1e-8)*2-1 ; 2+1e-8 == 2 in fp32 -> identity

    // silu
    float s = v / (1.0f + __expf(-v));
    Act[(size_t)b * KDIM + i] = f2bf(s);

    // cubic B-spline bases, closed form on uniform grid
    float t = (v + 2.2f) * 2.5f;                   // (v - t0)/h
    int m = (int)floorf(t);
    m = min(max(m, 2), 8);
    float u = t - (float)m;
    float u2 = u * u;
    float u3 = u2 * u;
    float p0 = u3 * (1.0f / 6.0f);                              // g = m
    float p1 = (1.0f + 3.0f * u + 3.0f * u2 - 3.0f * u3) * (1.0f / 6.0f); // g = m-1
    float p2 = (4.0f - 6.0f * u2 + 3.0f * u3) * (1.0f / 6.0f);  // g = m-2
    float w1 = 1.0f - u;
    float p3 = w1 * w1 * w1 * (1.0f / 6.0f);                    // g = m-3

    union { u16 us[8]; uint4 v4; } pk;
    #pragma unroll
    for (int g = 0; g < 8; ++g) {
        int j = m - g;
        float r = 0.0f;
        r = (j == 0) ? p0 : r;
        r = (j == 1) ? p1 : r;
        r = (j == 2) ? p2 : r;
        r = (j == 3) ? p3 : r;
        pk.us[g] = f2bf(r);
    }
    *reinterpret_cast<uint4*>(Act + (size_t)b * KDIM + IN_F + (size_t)i * 8) = pk.v4;
}

// ---------------- GEMM: C(16384x512) = Act(16384x4608) @ Wc(512x4608)^T --------
__global__ __launch_bounds__(256) void gemm_kernel(const u16* __restrict__ A,
                                                   const u16* __restrict__ Bw,
                                                   float* __restrict__ C) {
    __shared__ u16 As[BM * BK];
    __shared__ u16 Bs[BN * BK];

    const int tid  = threadIdx.x;
    const int w    = tid >> 6;
    const int lane = tid & 63;

    // XCD-bijective swizzle (nwg = 512, %8 == 0)
    const int nwg = gridDim.x;
    const int bid = blockIdx.x;
    const int wg  = (bid & 7) * (nwg >> 3) + (bid >> 3);
    const int bm0 = (wg >> 2) * BM;     // 4 N-blocks share an A panel
    const int bn0 = (wg & 3) * BN;

    const int wr = (w >> 1) * 64;       // wave's output sub-tile origin
    const int wc = (w & 1) * 64;

    f32x4 acc[4][4] = {};

    const int stage_off0 = (w * 4) * 512 + lane * 8;  // elements
    const int rA = lane & 15;
    const int kgrp = (lane >> 4) * 8;

    for (int kt = 0; kt < KDIM / BK; ++kt) {
        const int k0 = kt * BK;
        #pragma unroll
        for (int c = 0; c < 4; ++c) {
            int off = stage_off0 + c * 512;
            int row = off >> 6;
            int col = off & 63;
            const u16* ga = A  + (size_t)(bm0 + row) * KDIM + k0 + col;
            const u16* gb = Bw + (size_t)(bn0 + row) * KDIM + k0 + col;
            __builtin_amdgcn_global_load_lds(
                (const __attribute__((address_space(1))) uint32_t*)ga,
                (__attribute__((address_space(3))) uint32_t*)(As + off), 16, 0, 0);
            __builtin_amdgcn_global_load_lds(
                (const __attribute__((address_space(1))) uint32_t*)gb,
                (__attribute__((address_space(3))) uint32_t*)(Bs + off), 16, 0, 0);
        }
        __syncthreads();

        #pragma unroll
        for (int kk = 0; kk < 2; ++kk) {
            const int kcol = kk * 32 + kgrp;
            s16x8 af[4], bf[4];
            #pragma unroll
            for (int m = 0; m < 4; ++m)
                af[m] = *reinterpret_cast<const s16x8*>(&As[(wr + m * 16 + rA) * BK + kcol]);
            #pragma unroll
            for (int n = 0; n < 4; ++n)
                bf[n] = *reinterpret_cast<const s16x8*>(&Bs[(wc + n * 16 + rA) * BK + kcol]);
            #pragma unroll
            for (int m = 0; m < 4; ++m)
                #pragma unroll
                for (int n = 0; n < 4; ++n)
                    acc[m][n] = __builtin_amdgcn_mfma_f32_16x16x32_bf16(af[m], bf[n], acc[m][n], 0, 0, 0);
        }
        __syncthreads();
    }

    // epilogue: C/D layout col = lane&15, row = (lane>>4)*4 + reg
    const int rq = lane >> 4;
    const int cn = lane & 15;
    #pragma unroll
    for (int m = 0; m < 4; ++m) {
        #pragma unroll
        for (int n = 0; n < 4; ++n) {
            const int row0 = bm0 + wr + m * 16 + rq * 4;
            const int col  = bn0 + wc + n * 16 + cn;
            float* cp = C + (size_t)row0 * OUT_F + col;
            cp[0 * OUT_F] = acc[m][n][0];
            cp[1 * OUT_F] = acc[m][n][1];
            cp[2 * OUT_F] = acc[m][n][2];
            cp[3 * OUT_F] = acc[m][n][3];
        }
    }
}

extern "C" void kernel_launch(void* const* d_in, const int* in_sizes, int n_in,
                              void* d_out, int out_size, void* d_ws, size_t ws_size,
                              hipStream_t stream) {
    const float* x  = (const float*)d_in[0];
    const float* bw = (const float*)d_in[1];
    const float* sw = (const float*)d_in[2];
    const float* sc = (const float*)d_in[3];
    // d_in[4] (grid) unused: uniform knots by construction

    u16* Wc  = (u16*)d_ws;                         // 512*4608*2   = 4.7 MB
    u16* Act = Wc + (size_t)OUT_F * KDIM;          // 16384*4608*2 = 151 MB

    prep_w_kernel<<<(OUT_F * IN_F) / 256, 256, 0, stream>>>(bw, sw, sc, Wc);
    prep_x_kernel<<<(BATCH * IN_F) / 256, 256, 0, stream>>>(x, Act);
    gemm_kernel<<<(BATCH / BM) * (OUT_F / BN), 256, 0, stream>>>(Act, Wc, (float*)d_out);
}

// Round 2
// 128.332 us; speedup vs baseline: 1.1346x; 1.1346x over previous
//
#include <hip/hip_runtime.h>
#include <stdint.h>

// KANLinear: y = silu(x) @ W_b^T + einsum('big,oig->bo', bases(x), W_s * scaler)
// Strategy: materialize Act = [silu(x) | bases] (B x 4608) bf16 and
// Wc = [W_b | W_s*scaler] (512 x 4608) bf16, then one bf16 MFMA GEMM.
// R1: T2 LDS XOR-swizzle, baked into the workspace layout (pre-swizzled
// storage -> linear global_load_lds -> swizzled ds_read). Swizzle:
// element k of row r is stored at k ^ ((r&7)<<3)  (16B-chunk permutation).

#define IN_F   512
#define OUT_F  512
#define NB     8                     // GRID_SIZE + SPLINE_ORDER
#define KDIM   (IN_F + IN_F * NB)    // 4608
#define BATCH  16384

#define BM 128
#define BN 128
#define BK 64

typedef unsigned short u16;
typedef short s16x8 __attribute__((ext_vector_type(8)));
typedef float f32x4 __attribute__((ext_vector_type(4)));

__device__ __forceinline__ u16 f2bf(float f) {
    uint32_t u = __builtin_bit_cast(uint32_t, f);
    uint32_t r = (u + 0x7FFFu + ((u >> 16) & 1u)) >> 16;   // RNE
    return (u16)r;
}

// ---------------- weight prep: Wc[o][k] bf16 (pre-swizzled) --------------------
__global__ void prep_w_kernel(const float* __restrict__ bw,
                              const float* __restrict__ sw,
                              const float* __restrict__ sc,
                              u16* __restrict__ Wc) {
    int idx = blockIdx.x * 256 + threadIdx.x;      // (o,i), 512*512 threads
    int o = idx >> 9;
    int i = idx & 511;
    int swz = o & 7;
    Wc[(size_t)o * KDIM + (i ^ (swz << 3))] = f2bf(bw[idx]);
    float s = sc[idx];
    const float4* sp = reinterpret_cast<const float4*>(sw + (size_t)idx * 8);
    float4 a = sp[0];
    float4 b = sp[1];
    union { u16 us[8]; uint4 v; } pk;
    pk.us[0] = f2bf(a.x * s); pk.us[1] = f2bf(a.y * s);
    pk.us[2] = f2bf(a.z * s); pk.us[3] = f2bf(a.w * s);
    pk.us[4] = f2bf(b.x * s); pk.us[5] = f2bf(b.y * s);
    pk.us[6] = f2bf(b.z * s); pk.us[7] = f2bf(b.w * s);
    *reinterpret_cast<uint4*>(Wc + (size_t)o * KDIM + IN_F + (size_t)(i ^ swz) * 8) = pk.v;
}

// ---------------- activation prep: Act[b][*] bf16 (pre-swizzled) ---------------
// Uniform knots t_j = -2.2 + 0.4*j (j=0..11); x in [t_2, t_9) after clipping.
__global__ void prep_x_kernel(const float* __restrict__ x,
                              u16* __restrict__ Act) {
    int idx = blockIdx.x * 256 + threadIdx.x;      // (b,i), BATCH*IN_F threads
    int b = idx >> 9;
    int i = idx & 511;
    int swz = b & 7;
    float v = x[idx];
    if (v != v) v = 0.0f;                          // nan -> 0
    v = fminf(fmaxf(v, -6.0f), 6.0f);              // also folds +-inf
    v = fminf(fmaxf(v, -1.1f), 1.1f);              // grid clamp
    // renormalize: (x+1)/(2+1e-8)*2-1 ; 2+1e-8 == 2 in fp32 -> identity

    // silu
    float s = v / (1.0f + __expf(-v));
    Act[(size_t)b * KDIM + (i ^ (swz << 3))] = f2bf(s);

    // cubic B-spline bases, closed form on uniform grid
    float t = (v + 2.2f) * 2.5f;                   // (v - t0)/h
    int m = (int)floorf(t);
    m = min(max(m, 2), 8);
    float u = t - (float)m;
    float u2 = u * u;
    float u3 = u2 * u;
    float p0 = u3 * (1.0f / 6.0f);                              // g = m
    float p1 = (1.0f + 3.0f * u + 3.0f * u2 - 3.0f * u3) * (1.0f / 6.0f); // g = m-1
    float p2 = (4.0f - 6.0f * u2 + 3.0f * u3) * (1.0f / 6.0f);  // g = m-2
    float w1 = 1.0f - u;
    float p3 = w1 * w1 * w1 * (1.0f / 6.0f);                    // g = m-3

    union { u16 us[8]; uint4 v4; } pk;
    #pragma unroll
    for (int g = 0; g < 8; ++g) {
        int j = m - g;
        float r = 0.0f;
        r = (j == 0) ? p0 : r;
        r = (j == 1) ? p1 : r;
        r = (j == 2) ? p2 : r;
        r = (j == 3) ? p3 : r;
        pk.us[g] = f2bf(r);
    }
    *reinterpret_cast<uint4*>(Act + (size_t)b * KDIM + IN_F + (size_t)(i ^ swz) * 8) = pk.v4;
}

// ---------------- GEMM: C(16384x512) = Act(16384x4608) @ Wc(512x4608)^T --------
__global__ __launch_bounds__(256) void gemm_kernel(const u16* __restrict__ A,
                                                   const u16* __restrict__ Bw,
                                                   float* __restrict__ C) {
    __shared__ u16 As[BM * BK];
    __shared__ u16 Bs[BN * BK];

    const int tid  = threadIdx.x;
    const int w    = tid >> 6;
    const int lane = tid & 63;

    // XCD-bijective swizzle (nwg = 512, %8 == 0)
    const int nwg = gridDim.x;
    const int bid = blockIdx.x;
    const int wg  = (bid & 7) * (nwg >> 3) + (bid >> 3);
    const int bm0 = (wg >> 2) * BM;     // 4 N-blocks share an A panel
    const int bn0 = (wg & 3) * BN;

    const int wr = (w >> 1) * 64;       // wave's output sub-tile origin
    const int wc = (w & 1) * 64;

    f32x4 acc[4][4] = {};

    const int stage_off0 = (w * 4) * 512 + lane * 8;  // elements
    const int rA = lane & 15;
    const int sK = (rA & 7) << 3;       // ds_read column swizzle (elements)
    const int kgrp = (lane >> 4) * 8;

    for (int kt = 0; kt < KDIM / BK; ++kt) {
        const int k0 = kt * BK;
        #pragma unroll
        for (int c = 0; c < 4; ++c) {
            int off = stage_off0 + c * 512;
            int row = off >> 6;
            int col = off & 63;
            const u16* ga = A  + (size_t)(bm0 + row) * KDIM + k0 + col;
            const u16* gb = Bw + (size_t)(bn0 + row) * KDIM + k0 + col;
            __builtin_amdgcn_global_load_lds(
                (const __attribute__((address_space(1))) uint32_t*)ga,
                (__attribute__((address_space(3))) uint32_t*)(As + off), 16, 0, 0);
            __builtin_amdgcn_global_load_lds(
                (const __attribute__((address_space(1))) uint32_t*)gb,
                (__attribute__((address_space(3))) uint32_t*)(Bs + off), 16, 0, 0);
        }
        __syncthreads();

        #pragma unroll
        for (int kk = 0; kk < 2; ++kk) {
            const int kcol = (kk * 32 + kgrp) ^ sK;
            s16x8 af[4], bf[4];
            #pragma unroll
            for (int m = 0; m < 4; ++m)
                af[m] = *reinterpret_cast<const s16x8*>(&As[(wr + m * 16 + rA) * BK + kcol]);
            #pragma unroll
            for (int n = 0; n < 4; ++n)
                bf[n] = *reinterpret_cast<const s16x8*>(&Bs[(wc + n * 16 + rA) * BK + kcol]);
            #pragma unroll
            for (int m = 0; m < 4; ++m)
                #pragma unroll
                for (int n = 0; n < 4; ++n)
                    acc[m][n] = __builtin_amdgcn_mfma_f32_16x16x32_bf16(af[m], bf[n], acc[m][n], 0, 0, 0);
        }
        __syncthreads();
    }

    // epilogue: C/D layout col = lane&15, row = (lane>>4)*4 + reg
    const int rq = lane >> 4;
    const int cn = lane & 15;
    #pragma unroll
    for (int m = 0; m < 4; ++m) {
        #pragma unroll
        for (int n = 0; n < 4; ++n) {
            const int row0 = bm0 + wr + m * 16 + rq * 4;
            const int col  = bn0 + wc + n * 16 + cn;
            float* cp = C + (size_t)row0 * OUT_F + col;
            cp[0 * OUT_F] = acc[m][n][0];
            cp[1 * OUT_F] = acc[m][n][1];
            cp[2 * OUT_F] = acc[m][n][2];
            cp[3 * OUT_F] = acc[m][n][3];
        }
    }
}

extern "C" void kernel_launch(void* const* d_in, const int* in_sizes, int n_in,
                              void* d_out, int out_size, void* d_ws, size_t ws_size,
                              hipStream_t stream) {
    const float* x  = (const float*)d_in[0];
    const float* bw = (const float*)d_in[1];
    const float* sw = (const float*)d_in[2];
    const float* sc = (const float*)d_in[3];
    // d_in[4] (grid) unused: uniform knots by construction

    u16* Wc  = (u16*)d_ws;                         // 512*4608*2   = 4.7 MB
    u16* Act = Wc + (size_t)OUT_F * KDIM;          // 16384*4608*2 = 151 MB

    prep_w_kernel<<<(OUT_F * IN_F) / 256, 256, 0, stream>>>(bw, sw, sc, Wc);
    prep_x_kernel<<<(BATCH * IN_F) / 256, 256, 0, stream>>>(x, Act);
    gemm_kernel<<<(BATCH / BM) * (OUT_F / BN), 256, 0, stream>>>(Act, Wc, (float*)d_out);
}

// Round 3
// 115.240 us; speedup vs baseline: 1.2635x; 1.1136x over previous
//
#include <hip/hip_runtime.h>
#include <stdint.h>

// KANLinear: y = silu(x) @ W_b^T + einsum('big,oig->bo', bases(x), W_s * scaler)
// Materialize Act = [silu(x) | bases] (B x 4608) bf16 (pre-XOR-swizzled) and
// Wc = [W_b | W_s*scaler] (512 x 4608) bf16 (pre-swizzled), then one bf16 MFMA GEMM.
// R2: 8-phase-style deep pipeline (T3+T4+T5): BM256xBN128xBK64, 8 waves,
// ring of 3 LDS K-tile buffers, counted vmcnt(6), per-phase barriers+setprio.

#define IN_F   512
#define OUT_F  512
#define KDIM   4608
#define BATCH  16384

#define BM 256
#define BN 128
#define BK 64
#define NT (KDIM / BK)                 // 72
#define A_ELEMS (BM * BK)              // 16384 elems
#define B_ELEMS (BN * BK)              // 8192
#define TILE_ELEMS (A_ELEMS + B_ELEMS) // 24576 elems = 48 KiB
#define LDS_BYTES (3 * TILE_ELEMS * 2) // 147456 B

typedef unsigned short u16;
typedef short s16x8 __attribute__((ext_vector_type(8)));
typedef float f32x4 __attribute__((ext_vector_type(4)));

__device__ __forceinline__ u16 f2bf(float f) {
    uint32_t u = __builtin_bit_cast(uint32_t, f);
    uint32_t r = (u + 0x7FFFu + ((u >> 16) & 1u)) >> 16;   // RNE
    return (u16)r;
}

// ---------------- weight prep: Wc[o][k] bf16 (pre-swizzled) --------------------
__global__ void prep_w_kernel(const float* __restrict__ bw,
                              const float* __restrict__ sw,
                              const float* __restrict__ sc,
                              u16* __restrict__ Wc) {
    int idx = blockIdx.x * 256 + threadIdx.x;      // (o,i), 512*512 threads
    int o = idx >> 9;
    int i = idx & 511;
    int swz = o & 7;
    Wc[(size_t)o * KDIM + (i ^ (swz << 3))] = f2bf(bw[idx]);
    float s = sc[idx];
    const float4* sp = reinterpret_cast<const float4*>(sw + (size_t)idx * 8);
    float4 a = sp[0];
    float4 b = sp[1];
    union { u16 us[8]; uint4 v; } pk;
    pk.us[0] = f2bf(a.x * s); pk.us[1] = f2bf(a.y * s);
    pk.us[2] = f2bf(a.z * s); pk.us[3] = f2bf(a.w * s);
    pk.us[4] = f2bf(b.x * s); pk.us[5] = f2bf(b.y * s);
    pk.us[6] = f2bf(b.z * s); pk.us[7] = f2bf(b.w * s);
    *reinterpret_cast<uint4*>(Wc + (size_t)o * KDIM + IN_F + (size_t)(i ^ swz) * 8) = pk.v;
}

// ---------------- activation prep: Act[b][*] bf16 (pre-swizzled) ---------------
__global__ void prep_x_kernel(const float* __restrict__ x,
                              u16* __restrict__ Act) {
    int idx = blockIdx.x * 256 + threadIdx.x;      // (b,i), BATCH*IN_F threads
    int b = idx >> 9;
    int i = idx & 511;
    int swz = b & 7;
    float v = x[idx];
    if (v != v) v = 0.0f;                          // nan -> 0
    v = fminf(fmaxf(v, -6.0f), 6.0f);              // also folds +-inf
    v = fminf(fmaxf(v, -1.1f), 1.1f);              // grid clamp
    float s = v / (1.0f + __expf(-v));
    Act[(size_t)b * KDIM + (i ^ (swz << 3))] = f2bf(s);

    float t = (v + 2.2f) * 2.5f;                   // (v - t0)/h, h=0.4, t0=-2.2
    int m = (int)floorf(t);
    m = min(max(m, 2), 8);
    float u = t - (float)m;
    float u2 = u * u;
    float u3 = u2 * u;
    float p0 = u3 * (1.0f / 6.0f);
    float p1 = (1.0f + 3.0f * u + 3.0f * u2 - 3.0f * u3) * (1.0f / 6.0f);
    float p2 = (4.0f - 6.0f * u2 + 3.0f * u3) * (1.0f / 6.0f);
    float w1 = 1.0f - u;
    float p3 = w1 * w1 * w1 * (1.0f / 6.0f);

    union { u16 us[8]; uint4 v4; } pk;
    #pragma unroll
    for (int g = 0; g < 8; ++g) {
        int j = m - g;
        float r = 0.0f;
        r = (j == 0) ? p0 : r;
        r = (j == 1) ? p1 : r;
        r = (j == 2) ? p2 : r;
        r = (j == 3) ? p3 : r;
        pk.us[g] = f2bf(r);
    }
    *reinterpret_cast<uint4*>(Act + (size_t)b * KDIM + IN_F + (size_t)(i ^ swz) * 8) = pk.v4;
}

// ---------------- GEMM: C(16384x512) = Act(16384x4608) @ Wc(512x4608)^T --------
extern __shared__ u16 Sm[];

__global__ __launch_bounds__(512, 2) void gemm_kernel(const u16* __restrict__ A,
                                                      const u16* __restrict__ Bw,
                                                      float* __restrict__ C) {
    const int tid  = threadIdx.x;
    const int w    = tid >> 6;
    const int lane = tid & 63;

    // XCD-bijective swizzle, nwg = 256 (%8 == 0); 4 N-siblings adjacent per XCD
    const int bid = blockIdx.x;
    const int wg  = (bid & 7) * 32 + (bid >> 3);
    const int bm0 = (wg >> 2) * BM;
    const int bn0 = (wg & 3) * BN;

    const int wr = (w >> 1) * 64;       // 4 M-waves
    const int wc = (w & 1) * 64;        // 2 N-waves

    const int rA   = lane & 15;
    const int sK   = (rA & 7) << 3;     // ds_read column swizzle (elements)
    const int kgrp = (lane >> 4) * 8;
    const int offA = tid * 8;           // staging base elem offset

    f32x4 acc[4][4] = {};

    auto stageA = [&](u16* dst, int kt, int c) {
        int off = offA + c * 4096;
        int row = off >> 6, col = off & 63;
        const u16* g = A + (size_t)(bm0 + row) * KDIM + kt * BK + col;
        __builtin_amdgcn_global_load_lds(
            (const __attribute__((address_space(1))) uint32_t*)g,
            (__attribute__((address_space(3))) uint32_t*)(dst + off), 16, 0, 0);
    };
    auto stageB = [&](u16* dst, int kt, int c) {
        int off = offA + c * 4096;
        int row = off >> 6, col = off & 63;
        const u16* g = Bw + (size_t)(bn0 + row) * KDIM + kt * BK + col;
        __builtin_amdgcn_global_load_lds(
            (const __attribute__((address_space(1))) uint32_t*)g,
            (__attribute__((address_space(3))) uint32_t*)(dst + A_ELEMS + off), 16, 0, 0);
    };

    // prologue: stage tiles 0 and 1 (6 loads each, per thread)
    {
        u16* b0 = Sm;
        stageA(b0, 0, 0); stageA(b0, 0, 1); stageA(b0, 0, 2); stageA(b0, 0, 3);
        stageB(b0, 0, 0); stageB(b0, 0, 1);
        u16* b1 = Sm + TILE_ELEMS;
        stageA(b1, 1, 0); stageA(b1, 1, 1); stageA(b1, 1, 2); stageA(b1, 1, 3);
        stageB(b1, 1, 0); stageB(b1, 1, 1);
    }

#define PHASE(QM, KK, PFSTMT) do {                                                      \
    const int kc = ((KK) * 32 + kgrp) ^ sK;                                             \
    s16x8 af0 = *reinterpret_cast<const s16x8*>(&AsR[(wr + (QM)*32 +  0 + rA) * BK + kc]); \
    s16x8 af1 = *reinterpret_cast<const s16x8*>(&AsR[(wr + (QM)*32 + 16 + rA) * BK + kc]); \
    s16x8 bf0 = *reinterpret_cast<const s16x8*>(&BsR[(wc +  0 + rA) * BK + kc]);        \
    s16x8 bf1 = *reinterpret_cast<const s16x8*>(&BsR[(wc + 16 + rA) * BK + kc]);        \
    s16x8 bf2 = *reinterpret_cast<const s16x8*>(&BsR[(wc + 32 + rA) * BK + kc]);        \
    s16x8 bf3 = *reinterpret_cast<const s16x8*>(&BsR[(wc + 48 + rA) * BK + kc]);        \
    PFSTMT;                                                                             \
    __builtin_amdgcn_s_barrier();                                                       \
    asm volatile("s_waitcnt lgkmcnt(0)" ::: "memory");                                  \
    __builtin_amdgcn_s_setprio(1);                                                      \
    acc[(QM)*2+0][0] = __builtin_amdgcn_mfma_f32_16x16x32_bf16(af0, bf0, acc[(QM)*2+0][0], 0,0,0); \
    acc[(QM)*2+0][1] = __builtin_amdgcn_mfma_f32_16x16x32_bf16(af0, bf1, acc[(QM)*2+0][1], 0,0,0); \
    acc[(QM)*2+0][2] = __builtin_amdgcn_mfma_f32_16x16x32_bf16(af0, bf2, acc[(QM)*2+0][2], 0,0,0); \
    acc[(QM)*2+0][3] = __builtin_amdgcn_mfma_f32_16x16x32_bf16(af0, bf3, acc[(QM)*2+0][3], 0,0,0); \
    acc[(QM)*2+1][0] = __builtin_amdgcn_mfma_f32_16x16x32_bf16(af1, bf0, acc[(QM)*2+1][0], 0,0,0); \
    acc[(QM)*2+1][1] = __builtin_amdgcn_mfma_f32_16x16x32_bf16(af1, bf1, acc[(QM)*2+1][1], 0,0,0); \
    acc[(QM)*2+1][2] = __builtin_amdgcn_mfma_f32_16x16x32_bf16(af1, bf2, acc[(QM)*2+1][2], 0,0,0); \
    acc[(QM)*2+1][3] = __builtin_amdgcn_mfma_f32_16x16x32_bf16(af1, bf3, acc[(QM)*2+1][3], 0,0,0); \
    __builtin_amdgcn_s_setprio(0);                                                      \
} while (0)

    int rb = 0, wbuf = 2;
    for (int t = 0; t < NT; ++t) {
        // counted wait: tile t's 6 loads done, tile t+1's 6 stay in flight
        if (t < NT - 1) asm volatile("s_waitcnt vmcnt(6)" ::: "memory");
        else            asm volatile("s_waitcnt vmcnt(0)" ::: "memory");
        __builtin_amdgcn_s_barrier();

        u16* AsR = Sm + rb * TILE_ELEMS;
        u16* BsR = AsR + A_ELEMS;
        u16* Wb  = Sm + wbuf * TILE_ELEMS;
        const bool pf = (t + 2 < NT);

        PHASE(0, 0, if (pf) { stageA(Wb, t + 2, 0); stageA(Wb, t + 2, 1); });
        PHASE(1, 0, if (pf) { stageA(Wb, t + 2, 2); stageA(Wb, t + 2, 3); });
        PHASE(0, 1, if (pf) { stageB(Wb, t + 2, 0); });
        PHASE(1, 1, if (pf) { stageB(Wb, t + 2, 1); });

        rb   = (rb   == 2) ? 0 : rb + 1;
        wbuf = (wbuf == 2) ? 0 : wbuf + 1;
    }
#undef PHASE

    // epilogue: C/D layout col = lane&15, row = (lane>>4)*4 + reg
    const int rq = lane >> 4;
    const int cn = lane & 15;
    #pragma unroll
    for (int am = 0; am < 4; ++am) {
        #pragma unroll
        for (int an = 0; an < 4; ++an) {
            const int row0 = bm0 + wr + am * 16 + rq * 4;
            const int col  = bn0 + wc + an * 16 + cn;
            float* cp = C + (size_t)row0 * OUT_F + col;
            cp[0 * OUT_F] = acc[am][an][0];
            cp[1 * OUT_F] = acc[am][an][1];
            cp[2 * OUT_F] = acc[am][an][2];
            cp[3 * OUT_F] = acc[am][an][3];
        }
    }
}

extern "C" void kernel_launch(void* const* d_in, const int* in_sizes, int n_in,
                              void* d_out, int out_size, void* d_ws, size_t ws_size,
                              hipStream_t stream) {
    const float* x  = (const float*)d_in[0];
    const float* bw = (const float*)d_in[1];
    const float* sw = (const float*)d_in[2];
    const float* sc = (const float*)d_in[3];
    // d_in[4] (grid) unused: uniform knots by construction

    u16* Wc  = (u16*)d_ws;                         // 512*4608*2   = 4.7 MB
    u16* Act = Wc + (size_t)OUT_F * KDIM;          // 16384*4608*2 = 151 MB

    hipFuncSetAttribute((const void*)gemm_kernel,
                        hipFuncAttributeMaxDynamicSharedMemorySize, LDS_BYTES);

    prep_w_kernel<<<(OUT_F * IN_F) / 256, 256, 0, stream>>>(bw, sw, sc, Wc);
    prep_x_kernel<<<(BATCH * IN_F) / 256, 256, 0, stream>>>(x, Act);
    gemm_kernel<<<(BATCH / BM) * (OUT_F / BN), 512, LDS_BYTES, stream>>>(Act, Wc, (float*)d_out);
}